// Round 4
// baseline (293.814 us; speedup 1.0000x reference)
//
#include <hip/hip_runtime.h>
#include <hip/hip_bf16.h>

// out[b,e] = m[c,e] + sum_d z[b,d] * L[c,e,d],  c = components[b]
// fp32 in/out; bf16 MFMA inside. Round-4: split-K x4 -> 1280 blocks (real
// occupancy: 4 resident blocks/CU overlap barrier drains), fp32 partials in
// ws + reduce kernel (no atomics), wave-uniform skip of m-tiles >= cnt.

#define DDIM  2048
#define BSAMP 1024
#define KCOMP 10
#define MPAD  160
#define NT    64
#define BK    32
#define SPLITK 4
#define DCHUNK (DDIM / SPLITK)        // 512
#define ZREG  10240                   // 160 rows x 32 bf16 (64 B/row)
#define STAGE 18432                   // + 64 rows x 32 f32 (128 B/row)

typedef __attribute__((ext_vector_type(8))) short bf16x8;
typedef __attribute__((ext_vector_type(4))) float f32x4;

__device__ __forceinline__ void async16(void* lds, const void* g) {
    __builtin_amdgcn_global_load_lds(
        (const __attribute__((address_space(1))) void*)g,
        (__attribute__((address_space(3))) void*)lds, 16, 0, 0);
}
__device__ __forceinline__ short bfs(float x) {
    __hip_bfloat16 h = __float2bfloat16(x);
    return *reinterpret_cast<short*>(&h);
}
__device__ __forceinline__ bf16x8 packB(const char* rowb, int o0, int o1) {
    f32x4 x = *(const f32x4*)(rowb + o0);
    f32x4 y = *(const f32x4*)(rowb + o1);
    bf16x8 r;
#pragma unroll
    for (int i = 0; i < 4; ++i) { r[i] = bfs(x[i]); r[4 + i] = bfs(y[i]); }
    return r;
}

__global__ void build_map(const int* __restrict__ comp,
                          int* __restrict__ rowmap,
                          int* __restrict__ counts) {
    __shared__ int sc[KCOMP];
    const int t = threadIdx.x;
    if (t < KCOMP) sc[t] = 0;
    __syncthreads();
    const int c = comp[t];
    const int r = atomicAdd(&sc[c], 1);
    if (r < MPAD) rowmap[c * MPAD + r] = t;
    __syncthreads();
    if (t < KCOMP) counts[t] = sc[t];
}

__global__ void zconv(const float* __restrict__ z, short* __restrict__ zb) {
    const int i = (blockIdx.x * 256 + threadIdx.x) * 8;
    f32x4 a = *(const f32x4*)(z + i);
    f32x4 b = *(const f32x4*)(z + i + 4);
    bf16x8 o;
#pragma unroll
    for (int j = 0; j < 4; ++j) { o[j] = bfs(a[j]); o[4 + j] = bfs(b[j]); }
    *(bf16x8*)(zb + i) = o;
}

__device__ __forceinline__ int swz(int r) { return (r & 3) ^ ((r >> 2) & 3); }

// grid (32, 10, SPLITK), 256 thr (4 waves). Block tile 160x64, wave 80x32.
// Writes fp32 partial sums for d-range [kc*512, kc*512+512) to `partial`.
__global__ __launch_bounds__(256, 4)
void gmm_splitk(const short* __restrict__ zb,
                const float* __restrict__ Lmat,
                const int* __restrict__ rowmap,
                const int* __restrict__ counts,
                float* __restrict__ partial) {
    __shared__ __attribute__((aligned(16))) char smem[2 * STAGE];
    const int t = threadIdx.x, lane = t & 63;
    const int w = t >> 6, mh = w >> 1, nh = w & 1;
    const int k = blockIdx.y, n0 = blockIdx.x * NT;
    const int kc = blockIdx.z, dbase = kc * DCHUNK;
    const float* Lk = Lmat + (size_t)k * DDIM * DDIM;
    const int cnt = counts[k];

    // staging (slot-linear LDS, XOR-swizzled column data); see r3 comments
    const int zq = t >> 2, zcs = t & 3;
    const int zr1 = 64 + zq, zr2 = 128 + zq;
    const int rmB = k * MPAD;
    const int rm0 = rowmap[rmB + zq] & (BSAMP - 1);
    const int rm1 = rowmap[rmB + zr1] & (BSAMP - 1);
    const int rm2 = rowmap[rmB + ((zr2 < MPAD) ? zr2 : 0)] & (BSAMP - 1);
    const short* zp0 = zb + (size_t)rm0 * DDIM + dbase + (zcs ^ swz(zq)) * 8;
    const short* zp1 = zb + (size_t)rm1 * DDIM + dbase + (zcs ^ swz(zr1)) * 8;
    const short* zp2 = zb + (size_t)rm2 * DDIM + dbase + (zcs ^ swz(zr2)) * 8;
    const int lcs = t & 7;
    const int lr2 = (t >= 128) ? ((t - 128) >> 3) : 0;
    const int lr3 = 16 + (t >> 3);
    const int lr4 = 48 + (t >> 3);                      // t<128 only
    const float* lp2 = Lk + (size_t)(n0 + lr2) * DDIM + dbase + (lcs ^ (lr2 & 7)) * 4;
    const float* lp3 = Lk + (size_t)(n0 + lr3) * DDIM + dbase + (lcs ^ (lr3 & 7)) * 4;
    const float* lp4 = Lk + (size_t)(n0 + (lr4 & 63)) * DDIM + dbase + (lcs ^ (lr4 & 7)) * 4;
    const int ub  = (t & ~63) << 4;
    const int ubh = ((t - 128) & ~63) << 4;
    const bool lowHalf = (t < 128);
    const bool st1 = (cnt > 64), st2 = (cnt > 128);

    auto stage = [&](int buf, int it) {
        char* lb = smem + buf * STAGE;
        const int d = it * BK;
        async16(lb + ub, zp0 + d);
        if (st1) async16(lb + 4096 + ub, zp1 + d);
        if (lowHalf) {
            if (st2) async16(lb + 8192 + ub, zp2 + d);
            async16(lb + ZREG + 6144 + ub, lp4 + d);    // L rows 48..63
        } else {
            async16(lb + ZREG + ubh, lp2 + d);          // L rows 0..15
        }
        async16(lb + ZREG + 2048 + ub, lp3 + d);        // L rows 16..47
    };

    f32x4 acc[5][2];
#pragma unroll
    for (int mt = 0; mt < 5; ++mt)
#pragma unroll
        for (int nt = 0; nt < 2; ++nt) acc[mt][nt] = (f32x4){0.f, 0.f, 0.f, 0.f};

    stage(0, 0);
    __syncthreads();

    const int fr = lane & 15, g = lane >> 4;
    const int szA   = (fr & 3) ^ ((fr >> 2) & 3);
    const int aoff  = ((g ^ szA) & 3) * 16;
    const int boff0 = (((g * 2)     ^ (fr & 7)) & 7) * 16;
    const int boff1 = (((g * 2 + 1) ^ (fr & 7)) & 7) * 16;
    const int rb0 = (nh * 32 + fr) * 128, rb1 = (nh * 32 + 16 + fr) * 128;
    const int raB = (mh * 80 + fr) * 64;

    for (int it = 0; it < DCHUNK / BK; ++it) {          // 16 iters
        if (it + 1 < DCHUNK / BK) stage((it + 1) & 1, it + 1);
        const char* lb = smem + (it & 1) * STAGE;
        const char* Lb = lb + ZREG;
        bf16x8 b0 = packB(Lb + rb0, boff0, boff1);
        bf16x8 b1 = packB(Lb + rb1, boff0, boff1);
#pragma unroll
        for (int mt = 0; mt < 5; ++mt) {
            if (mh * 80 + mt * 16 < cnt) {              // wave-uniform skip
                bf16x8 a = *(const bf16x8*)(lb + raB + mt * 16 * 64 + aoff);
                acc[mt][0] = __builtin_amdgcn_mfma_f32_16x16x32_bf16(a, b0, acc[mt][0], 0, 0, 0);
                acc[mt][1] = __builtin_amdgcn_mfma_f32_16x16x32_bf16(a, b1, acc[mt][1], 0, 0, 0);
            }
        }
        __syncthreads();
    }

    // epilogue: C/D col=lane&15, row=(lane>>4)*4+reg -> fp32 partial slice kc
    float* pk = partial + (size_t)kc * BSAMP * DDIM;
    const int rquad = (lane >> 4) * 4;
#pragma unroll
    for (int nt = 0; nt < 2; ++nt) {
        const int e = n0 + nh * 32 + nt * 16 + fr;
#pragma unroll
        for (int mt = 0; mt < 5; ++mt) {
            const int sb = mh * 80 + mt * 16 + rquad;
#pragma unroll
            for (int r = 0; r < 4; ++r) {
                const int slot = sb + r;
                if (slot < cnt) {
                    const int b = rowmap[rmB + slot];
                    pk[(size_t)b * DDIM + e] = acc[mt][nt][r];
                }
            }
        }
    }
}

// out[b,e] = m[comp[b],e] + sum_kc partial[kc][b][e].  grid 1024 x 256.
__global__ void reduce_out(const float* __restrict__ partial,
                           const float* __restrict__ mvec,
                           const int* __restrict__ comp,
                           float* __restrict__ out) {
    const int b = blockIdx.x;
    const int c = comp[b];
    const int e = threadIdx.x * 8;
    const float* pb = partial + (size_t)b * DDIM + e;
    f32x4 s0 = *(const f32x4*)(mvec + (size_t)c * DDIM + e);
    f32x4 s1 = *(const f32x4*)(mvec + (size_t)c * DDIM + e + 4);
#pragma unroll
    for (int kc = 0; kc < SPLITK; ++kc) {
        const float* p = pb + (size_t)kc * BSAMP * DDIM;
        s0 += *(const f32x4*)(p);
        s1 += *(const f32x4*)(p + 4);
    }
    *(f32x4*)(out + (size_t)b * DDIM + e)     = s0;
    *(f32x4*)(out + (size_t)b * DDIM + e + 4) = s1;
}

// ---------------- fallback (round-2 proven): fp32 staging, tiny ws ---------
__device__ __forceinline__ bf16x8 frag8(const char* base, int o0, int o1) {
    f32x4 x = *(const f32x4*)(base + o0);
    f32x4 y = *(const f32x4*)(base + o1);
    bf16x8 r;
#pragma unroll
    for (int i = 0; i < 4; ++i) { r[i] = bfs(x[i]); r[4 + i] = bfs(y[i]); }
    return r;
}
__global__ __launch_bounds__(256, 2)
void gmm_f32z(const float* __restrict__ z, const float* __restrict__ mvec,
              const float* __restrict__ Lmat, const int* __restrict__ rowmap,
              const int* __restrict__ counts, float* __restrict__ out) {
    __shared__ __attribute__((aligned(16))) char smem[2 * 28672];
    const int t = threadIdx.x, lane = t & 63, w = t >> 6;
    const int mh = w >> 1, nh = w & 1;
    const int k = blockIdx.y, n0 = blockIdx.x * NT;
    const float* Lk = Lmat + (size_t)k * DDIM * DDIM;
    const int rq = t >> 3;
    const int scol = ((t & 7) ^ (rq & 7)) * 4;
    int rm[5];
#pragma unroll
    for (int j = 0; j < 5; ++j)
        rm[j] = rowmap[k * MPAD + j * 32 + rq] & (BSAMP - 1);
    const unsigned ub = (unsigned)(t & ~63) * 16;
    auto stage = [&](int buf, int it) {
        char* lb = smem + buf * 28672;
        const int d0 = it * 32 + scol;
#pragma unroll
        for (int j = 0; j < 5; ++j)
            async16(lb + j * 4096 + ub, z + (size_t)rm[j] * DDIM + d0);
        async16(lb + 20480 + ub,        Lk + (size_t)(n0 + rq) * DDIM + d0);
        async16(lb + 20480 + 4096 + ub, Lk + (size_t)(n0 + 32 + rq) * DDIM + d0);
    };
    f32x4 acc[5][2];
#pragma unroll
    for (int mt = 0; mt < 5; ++mt)
#pragma unroll
        for (int nt = 0; nt < 2; ++nt) acc[mt][nt] = (f32x4){0.f, 0.f, 0.f, 0.f};
    stage(0, 0);
    __syncthreads();
    const int fr = lane & 15, g0 = (lane >> 4) * 2;
    for (int it = 0; it < DDIM / 32; ++it) {
        if (it + 1 < DDIM / 32) stage((it + 1) & 1, it + 1);
        const char* lb = smem + (it & 1) * 28672;
        const int rb0 = nh * 32 + fr, rb1 = rb0 + 16;
        bf16x8 b0 = frag8(lb + 20480, rb0 * 128 + ((g0 ^ rb0) & 7) * 16,
                          rb0 * 128 + (((g0 + 1) ^ rb0) & 7) * 16);
        bf16x8 b1 = frag8(lb + 20480, rb1 * 128 + ((g0 ^ rb1) & 7) * 16,
                          rb1 * 128 + (((g0 + 1) ^ rb1) & 7) * 16);
#pragma unroll
        for (int mt = 0; mt < 5; ++mt) {
            const int ra = mh * 80 + mt * 16 + fr;
            bf16x8 a = frag8(lb, ra * 128 + ((g0 ^ ra) & 7) * 16,
                             ra * 128 + (((g0 + 1) ^ ra) & 7) * 16);
            acc[mt][0] = __builtin_amdgcn_mfma_f32_16x16x32_bf16(a, b0, acc[mt][0], 0, 0, 0);
            acc[mt][1] = __builtin_amdgcn_mfma_f32_16x16x32_bf16(a, b1, acc[mt][1], 0, 0, 0);
        }
        __syncthreads();
    }
    const int cnt = counts[k], rquad = (lane >> 4) * 4;
#pragma unroll
    for (int nt = 0; nt < 2; ++nt) {
        const int e = n0 + nh * 32 + nt * 16 + fr;
        const float mu = mvec[k * DDIM + e];
#pragma unroll
        for (int mt = 0; mt < 5; ++mt) {
            const int sb = mh * 80 + mt * 16 + rquad;
#pragma unroll
            for (int r = 0; r < 4; ++r) {
                const int slot = sb + r;
                if (slot < cnt)
                    out[(size_t)rowmap[k * MPAD + slot] * DDIM + e] = acc[mt][nt][r] + mu;
            }
        }
    }
}

extern "C" void kernel_launch(void* const* d_in, const int* in_sizes, int n_in,
                              void* d_out, int out_size, void* d_ws, size_t ws_size,
                              hipStream_t stream) {
    const float* z    = (const float*)d_in[0];
    const float* mvec = (const float*)d_in[1];
    const float* Lmat = (const float*)d_in[2];
    const int* comp   = (const int*)d_in[3];
    float* out        = (float*)d_out;

    int* rowmap = (int*)d_ws;                     // 6400 B (+counts)
    int* counts = rowmap + KCOMP * MPAD;
    build_map<<<1, BSAMP, 0, stream>>>(comp, rowmap, counts);

    const size_t zb_off = 8192;
    const size_t zb_sz  = (size_t)BSAMP * DDIM * 2;              // 4 MB
    const size_t p_off  = zb_off + zb_sz;                        // 16B aligned
    const size_t p_sz   = (size_t)SPLITK * BSAMP * DDIM * 4;     // 32 MB

    if (ws_size >= p_off + p_sz) {
        short* zbuf    = (short*)((char*)d_ws + zb_off);
        float* partial = (float*)((char*)d_ws + p_off);
        zconv<<<BSAMP * DDIM / (256 * 8), 256, 0, stream>>>(z, zbuf);
        gmm_splitk<<<dim3(DDIM / NT, KCOMP, SPLITK), 256, 0, stream>>>(
            zbuf, Lmat, rowmap, counts, partial);
        reduce_out<<<BSAMP, DDIM / 8, 0, stream>>>(partial, mvec, comp, out);
    } else {
        gmm_f32z<<<dim3(DDIM / NT, KCOMP), 256, 0, stream>>>(
            z, mvec, Lmat, rowmap, counts, out);
    }
}

// Round 5
// 286.969 us; speedup vs baseline: 1.0239x; 1.0239x over previous
//
#include <hip/hip_runtime.h>
#include <hip/hip_bf16.h>

// out[b,e] = m[c,e] + sum_d z[b,d] * L[c,e,d],  c = components[b]
// fp32 in/out; bf16 MFMA. Round-5: LDS-FREE direct-to-register GEMM.
// No __syncthreads in the K-loop -> compiler emits fine-grained vmcnt(N)
// software pipelining (AITER pattern). A-operand (z) pre-packed into ws in
// exact MFMA fragment order (1 contiguous 16B load/lane/mtile); B-operand
// read straight from L (8 contig fp32/lane), cvt to bf16 in-register.
// Grid (64 n-tiles, 10 comps, 2 m-halves) = 1280 blocks = 5.0/CU balanced.

#define DDIM  2048
#define BSAMP 1024
#define KCOMP 10
#define MPAD  160

typedef __attribute__((ext_vector_type(8))) short bf16x8;
typedef __attribute__((ext_vector_type(4))) float f32x4;

__device__ __forceinline__ short bfs(float x) {
    __hip_bfloat16 h = __float2bfloat16(x);
    return *reinterpret_cast<short*>(&h);
}

__global__ void build_map(const int* __restrict__ comp,
                          int* __restrict__ rowmap,
                          int* __restrict__ counts) {
    __shared__ int sc[KCOMP];
    const int t = threadIdx.x;
    if (t < KCOMP) sc[t] = 0;
    __syncthreads();
    const int c = comp[t];
    const int r = atomicAdd(&sc[c], 1);
    if (r < MPAD) rowmap[c * MPAD + r] = t;
    __syncthreads();
    if (t < KCOMP) counts[t] = sc[t];
}

// Pack z into A-fragment order: zfrag[((k*64+it)*10+ms)*64+lane] (16B items).
// Item = z[rowmap[k][ms*16+(lane&15)]][it*32+(lane>>4)*8 .. +8) as bf16x8.
// 409600 items -> grid 1600 x 256, one item/thread, writes fully coalesced.
__global__ void zprep(const float* __restrict__ z,
                      const int* __restrict__ rowmap,
                      short* __restrict__ zfrag) {
    const int idx  = blockIdx.x * 256 + threadIdx.x;
    const int lane = idx & 63;
    const int rest = idx >> 6;          // (k*64+it)*10+ms
    const int ms   = rest % 10;
    const int kit  = rest / 10;         // k*64+it
    const int it   = kit & 63;
    const int k    = kit >> 6;
    const int slot = ms * 16 + (lane & 15);
    const int r    = rowmap[k * MPAD + slot] & (BSAMP - 1);   // pad-masked
    const int d    = it * 32 + (lane >> 4) * 8;
    const float* zp = z + (size_t)r * DDIM + d;
    f32x4 a = *(const f32x4*)zp;
    f32x4 b = *(const f32x4*)(zp + 4);
    bf16x8 o;
#pragma unroll
    for (int j = 0; j < 4; ++j) { o[j] = bfs(a[j]); o[4 + j] = bfs(b[j]); }
    *(bf16x8*)(zfrag + (size_t)idx * 8) = o;
}

// K-loop + epilogue, specialized on block-uniform active m-tile count MT.
template <int MT>
__device__ __forceinline__ void gmm_body(
        const short* __restrict__ Ab,      // A frags, this (k, mh), lane-offset
        const float* __restrict__ Bp,      // L row base for this lane
        const float* __restrict__ mvec,
        const int* __restrict__ rowmap,
        float* __restrict__ out,
        int k, int mh, int e, int cnt, int lane) {
    f32x4 acc[MT];
#pragma unroll
    for (int mt = 0; mt < MT; ++mt) acc[mt] = (f32x4){0.f, 0.f, 0.f, 0.f};

#pragma unroll 2
    for (int it = 0; it < DDIM / 32; ++it) {
        f32x4 bx = *(const f32x4*)(Bp);
        f32x4 by = *(const f32x4*)(Bp + 4);
        bf16x8 b;
#pragma unroll
        for (int j = 0; j < 4; ++j) { b[j] = bfs(bx[j]); b[4 + j] = bfs(by[j]); }
#pragma unroll
        for (int mt = 0; mt < MT; ++mt) {
            bf16x8 a = *(const bf16x8*)(Ab + mt * 512);
            acc[mt] = __builtin_amdgcn_mfma_f32_16x16x32_bf16(a, b, acc[mt], 0, 0, 0);
        }
        Ab += 5120;                       // next it: 10 mslots * 512 shorts
        Bp += 32;                         // next 32 d's
    }

    // C/D: col = lane&15 (= e), row = (lane>>4)*4 + reg
    const float mu  = mvec[k * DDIM + e];
    const int rquad = (lane >> 4) * 4;
    const int rmB   = k * MPAD;
#pragma unroll
    for (int mt = 0; mt < MT; ++mt) {
        const int sb = mh * 80 + mt * 16 + rquad;
#pragma unroll
        for (int r = 0; r < 4; ++r) {
            const int slot = sb + r;
            if (slot < cnt) {
                const int bidx = rowmap[rmB + slot];
                out[(size_t)bidx * DDIM + e] = acc[mt][r] + mu;
            }
        }
    }
}

// grid (64, 10, 2), 128 thr (2 waves, nh = wave id). Wave tile 80 x 16.
__global__ __launch_bounds__(128, 4)
void gmm_direct(const short* __restrict__ zfrag,
                const float* __restrict__ mvec,
                const float* __restrict__ Lmat,
                const int* __restrict__ rowmap,
                const int* __restrict__ counts,
                float* __restrict__ out) {
    const int t = threadIdx.x, lane = t & 63, nh = t >> 6;
    const int n  = blockIdx.x;            // n-tile (32 cols)
    const int k  = blockIdx.y;            // component
    const int mh = blockIdx.z;            // m-half (80 rows)
    const int cnt = counts[k];
    const int rem = cnt - mh * 80;
    if (rem <= 0) return;                 // no barriers -> safe early exit
    const int nmt = (rem >= 80) ? 5 : ((rem + 15) >> 4);

    const int e = n * 32 + nh * 16 + (lane & 15);
    const short* Ab = zfrag + ((size_t)(k * 64) * 10 + mh * 5) * 512 + lane * 8;
    const float* Bp = Lmat + (size_t)k * DDIM * DDIM + (size_t)e * DDIM
                    + (lane >> 4) * 8;

    switch (nmt) {
        case 5: gmm_body<5>(Ab, Bp, mvec, rowmap, out, k, mh, e, cnt, lane); break;
        case 4: gmm_body<4>(Ab, Bp, mvec, rowmap, out, k, mh, e, cnt, lane); break;
        case 3: gmm_body<3>(Ab, Bp, mvec, rowmap, out, k, mh, e, cnt, lane); break;
        case 2: gmm_body<2>(Ab, Bp, mvec, rowmap, out, k, mh, e, cnt, lane); break;
        default: gmm_body<1>(Ab, Bp, mvec, rowmap, out, k, mh, e, cnt, lane); break;
    }
}

// ---------------- fallback (round-2 proven): fp32 LDS staging, tiny ws -----
typedef bf16x8 bf8_t;
__device__ __forceinline__ void async16(void* lds, const void* g) {
    __builtin_amdgcn_global_load_lds(
        (const __attribute__((address_space(1))) void*)g,
        (__attribute__((address_space(3))) void*)lds, 16, 0, 0);
}
__device__ __forceinline__ bf16x8 frag8(const char* base, int o0, int o1) {
    f32x4 x = *(const f32x4*)(base + o0);
    f32x4 y = *(const f32x4*)(base + o1);
    bf16x8 r;
#pragma unroll
    for (int i = 0; i < 4; ++i) { r[i] = bfs(x[i]); r[4 + i] = bfs(y[i]); }
    return r;
}
__global__ __launch_bounds__(256, 2)
void gmm_f32z(const float* __restrict__ z, const float* __restrict__ mvec,
              const float* __restrict__ Lmat, const int* __restrict__ rowmap,
              const int* __restrict__ counts, float* __restrict__ out) {
    __shared__ __attribute__((aligned(16))) char smem[2 * 28672];
    const int t = threadIdx.x, lane = t & 63, w = t >> 6;
    const int mh = w >> 1, nh = w & 1;
    const int k = blockIdx.y, n0 = blockIdx.x * 64;
    const float* Lk = Lmat + (size_t)k * DDIM * DDIM;
    const int rq = t >> 3;
    const int scol = ((t & 7) ^ (rq & 7)) * 4;
    int rm[5];
#pragma unroll
    for (int j = 0; j < 5; ++j)
        rm[j] = rowmap[k * MPAD + j * 32 + rq] & (BSAMP - 1);
    const unsigned ub = (unsigned)(t & ~63) * 16;
    auto stage = [&](int buf, int it) {
        char* lb = smem + buf * 28672;
        const int d0 = it * 32 + scol;
#pragma unroll
        for (int j = 0; j < 5; ++j)
            async16(lb + j * 4096 + ub, z + (size_t)rm[j] * DDIM + d0);
        async16(lb + 20480 + ub,        Lk + (size_t)(n0 + rq) * DDIM + d0);
        async16(lb + 20480 + 4096 + ub, Lk + (size_t)(n0 + 32 + rq) * DDIM + d0);
    };
    f32x4 acc[5][2];
#pragma unroll
    for (int mt = 0; mt < 5; ++mt)
#pragma unroll
        for (int nt = 0; nt < 2; ++nt) acc[mt][nt] = (f32x4){0.f, 0.f, 0.f, 0.f};
    stage(0, 0);
    __syncthreads();
    const int fr = lane & 15, g0 = (lane >> 4) * 2;
    for (int it = 0; it < DDIM / 32; ++it) {
        if (it + 1 < DDIM / 32) stage((it + 1) & 1, it + 1);
        const char* lb = smem + (it & 1) * 28672;
        const int rb0 = nh * 32 + fr, rb1 = rb0 + 16;
        bf16x8 b0 = frag8(lb + 20480, rb0 * 128 + ((g0 ^ rb0) & 7) * 16,
                          rb0 * 128 + (((g0 + 1) ^ rb0) & 7) * 16);
        bf16x8 b1 = frag8(lb + 20480, rb1 * 128 + ((g0 ^ rb1) & 7) * 16,
                          rb1 * 128 + (((g0 + 1) ^ rb1) & 7) * 16);
#pragma unroll
        for (int mt = 0; mt < 5; ++mt) {
            const int ra = mh * 80 + mt * 16 + fr;
            bf16x8 a = frag8(lb, ra * 128 + ((g0 ^ ra) & 7) * 16,
                             ra * 128 + (((g0 + 1) ^ ra) & 7) * 16);
            acc[mt][0] = __builtin_amdgcn_mfma_f32_16x16x32_bf16(a, b0, acc[mt][0], 0, 0, 0);
            acc[mt][1] = __builtin_amdgcn_mfma_f32_16x16x32_bf16(a, b1, acc[mt][1], 0, 0, 0);
        }
        __syncthreads();
    }
    const int cnt = counts[k], rquad = (lane >> 4) * 4;
#pragma unroll
    for (int nt = 0; nt < 2; ++nt) {
        const int e = n0 + nh * 32 + nt * 16 + fr;
        const float mu = mvec[k * DDIM + e];
#pragma unroll
        for (int mt = 0; mt < 5; ++mt) {
            const int sb = mh * 80 + mt * 16 + rquad;
#pragma unroll
            for (int r = 0; r < 4; ++r) {
                const int slot = sb + r;
                if (slot < cnt)
                    out[(size_t)rowmap[k * MPAD + slot] * DDIM + e] = acc[mt][nt][r] + mu;
            }
        }
    }
}

extern "C" void kernel_launch(void* const* d_in, const int* in_sizes, int n_in,
                              void* d_out, int out_size, void* d_ws, size_t ws_size,
                              hipStream_t stream) {
    const float* z    = (const float*)d_in[0];
    const float* mvec = (const float*)d_in[1];
    const float* Lmat = (const float*)d_in[2];
    const int* comp   = (const int*)d_in[3];
    float* out        = (float*)d_out;

    int* rowmap = (int*)d_ws;                     // 6400 B (+counts)
    int* counts = rowmap + KCOMP * MPAD;
    build_map<<<1, BSAMP, 0, stream>>>(comp, rowmap, counts);

    const size_t zf_off = 8192;
    const size_t zf_sz  = (size_t)KCOMP * 64 * 10 * 64 * 16;   // 6.4 MB

    if (ws_size >= zf_off + zf_sz) {
        short* zfrag = (short*)((char*)d_ws + zf_off);
        zprep<<<1600, 256, 0, stream>>>(z, rowmap, zfrag);
        gmm_direct<<<dim3(64, KCOMP, 2), 128, 0, stream>>>(
            zfrag, mvec, Lmat, rowmap, counts, out);
    } else {
        gmm_f32z<<<dim3(32, KCOMP), 256, 0, stream>>>(
            z, mvec, Lmat, rowmap, counts, out);
    }
}

// Round 6
// 279.766 us; speedup vs baseline: 1.0502x; 1.0257x over previous
//
#include <hip/hip_runtime.h>
#include <hip/hip_bf16.h>

// out[b,e] = m[c,e] + sum_d z[b,d] * L[c,e,d],  c = components[b]
// fp32 in/out; bf16 MFMA. Round-6: LDS-free direct GEMM with EXPLICIT
// register-rotated software pipeline: B (L-stream, HBM) depth-8 window,
// A (zfrag, L2/L3) depth-1 ping-pong. No barriers; fully-unrolled inner 8
// so all buffer indices are compile-time. Grid pairs (n, mh) adjacently so
// the 2x L re-read is L3-resident.

#define DDIM  2048
#define BSAMP 1024
#define KCOMP 10
#define MPAD  160

typedef __attribute__((ext_vector_type(8))) short bf16x8;
typedef __attribute__((ext_vector_type(4))) float f32x4;

__device__ __forceinline__ short bfs(float x) {
    __hip_bfloat16 h = __float2bfloat16(x);
    return *reinterpret_cast<short*>(&h);
}

__global__ void build_map(const int* __restrict__ comp,
                          int* __restrict__ rowmap,
                          int* __restrict__ counts) {
    __shared__ int sc[KCOMP];
    const int t = threadIdx.x;
    if (t < KCOMP) sc[t] = 0;
    __syncthreads();
    const int c = comp[t];
    const int r = atomicAdd(&sc[c], 1);
    if (r < MPAD) rowmap[c * MPAD + r] = t;
    __syncthreads();
    if (t < KCOMP) counts[t] = sc[t];
}

// Pack z into A-fragment order: zfrag[((k*64+it)*10+ms)*64+lane] (16B items).
__global__ void zprep(const float* __restrict__ z,
                      const int* __restrict__ rowmap,
                      short* __restrict__ zfrag) {
    const int idx  = blockIdx.x * 256 + threadIdx.x;
    const int lane = idx & 63;
    const int rest = idx >> 6;
    const int ms   = rest % 10;
    const int kit  = rest / 10;
    const int it   = kit & 63;
    const int k    = kit >> 6;
    const int slot = ms * 16 + (lane & 15);
    const int r    = rowmap[k * MPAD + slot] & (BSAMP - 1);
    const int d    = it * 32 + (lane >> 4) * 8;
    const float* zp = z + (size_t)r * DDIM + d;
    f32x4 a = *(const f32x4*)zp;
    f32x4 b = *(const f32x4*)(zp + 4);
    bf16x8 o;
#pragma unroll
    for (int j = 0; j < 4; ++j) { o[j] = bfs(a[j]); o[4 + j] = bfs(b[j]); }
    *(bf16x8*)(zfrag + (size_t)idx * 8) = o;
}

template <int MT>
__device__ __forceinline__ void gmm_body(
        const short* __restrict__ Ap,      // A frags base (it=0), +lane*8
        const float* __restrict__ Bp,      // L row base for this lane
        const float* __restrict__ mvec,
        const int* __restrict__ rowmap,
        float* __restrict__ out,
        int k, int mh, int e, int cnt, int lane) {
    f32x4 acc[MT];
#pragma unroll
    for (int mt = 0; mt < MT; ++mt) acc[mt] = (f32x4){0.f, 0.f, 0.f, 0.f};

    // ---- pipeline state ----
    f32x4 Bw[8][2];                       // B window: iters it..it+7
    bf16x8 A0[MT], A1[MT];                // A ping-pong: it, it+1
#pragma unroll
    for (int j = 0; j < 8; ++j) {
        Bw[j][0] = *(const f32x4*)(Bp + j * 32);
        Bw[j][1] = *(const f32x4*)(Bp + j * 32 + 4);
    }
#pragma unroll
    for (int mt = 0; mt < MT; ++mt) A0[mt] = *(const bf16x8*)(Ap + mt * 512);

    const float* Bpf = Bp + 8 * 32;       // refill target: it+8
    const short* Apf = Ap + 5120;         // prefetch target: it+1
    int it = 0;

    auto step = [&](bf16x8* Ac, bf16x8* An, f32x4* Bs) {
        // 1) issue A prefetch for it+1 (covers L2/L3 latency with this step)
#pragma unroll
        for (int mt = 0; mt < MT; ++mt) An[mt] = *(const bf16x8*)(Apf + mt * 512);
        // 2) issue B refill for it+8 BEFORE consuming (keeps 8 groups in flight)
        f32x4 nb0 = *(const f32x4*)(Bpf);
        f32x4 nb1 = *(const f32x4*)(Bpf + 4);
        // 3) consume current B slot (loaded 8 iters ago -> latency hidden)
        bf16x8 b;
#pragma unroll
        for (int j = 0; j < 4; ++j) { b[j] = bfs(Bs[0][j]); b[4 + j] = bfs(Bs[1][j]); }
        // 4) MFMA with A loaded last step
#pragma unroll
        for (int mt = 0; mt < MT; ++mt)
            acc[mt] = __builtin_amdgcn_mfma_f32_16x16x32_bf16(Ac[mt], b, acc[mt], 0, 0, 0);
        Bs[0] = nb0; Bs[1] = nb1;
        // 5) advance (scalar-uniform selects; clamped tails are discarded)
        ++it;
        if (it < 63) Apf += 5120;
        if (it < 56) Bpf += 32;
    };

    for (int ot = 0; ot < 8; ++ot) {
        step(A0, A1, Bw[0]); step(A1, A0, Bw[1]);
        step(A0, A1, Bw[2]); step(A1, A0, Bw[3]);
        step(A0, A1, Bw[4]); step(A1, A0, Bw[5]);
        step(A0, A1, Bw[6]); step(A1, A0, Bw[7]);
    }

    // epilogue: C/D col=lane&15, row=(lane>>4)*4+reg
    const float mu  = mvec[k * DDIM + e];
    const int rquad = (lane >> 4) * 4;
    const int rmB   = k * MPAD;
#pragma unroll
    for (int mt = 0; mt < MT; ++mt) {
        const int sb = mh * 80 + mt * 16 + rquad;
#pragma unroll
        for (int r = 0; r < 4; ++r) {
            const int slot = sb + r;
            if (slot < cnt) {
                const int bidx = rowmap[rmB + slot];
                out[(size_t)bidx * DDIM + e] = acc[mt][r] + mu;
            }
        }
    }
}

// grid (128, 10): x = n*2+mh  (pairs adjacent -> L3 reuse of L rows).
// 128 thr = 2 waves (nh = wave id). Wave tile 80 x 16.
__global__ __launch_bounds__(128, 2)
void gmm_direct(const short* __restrict__ zfrag,
                const float* __restrict__ mvec,
                const float* __restrict__ Lmat,
                const int* __restrict__ rowmap,
                const int* __restrict__ counts,
                float* __restrict__ out) {
    const int t = threadIdx.x, lane = t & 63, nh = t >> 6;
    const int n  = blockIdx.x >> 1;
    const int mh = blockIdx.x & 1;
    const int k  = blockIdx.y;
    const int cnt = counts[k];
    const int rem = cnt - mh * 80;
    if (rem <= 0) return;                 // no barriers -> safe early exit
    const int nmt = (rem >= 80) ? 5 : ((rem + 15) >> 4);

    const int e = n * 32 + nh * 16 + (lane & 15);
    const short* Ap = zfrag + ((size_t)(k * 64) * 10 + mh * 5) * 512 + lane * 8;
    const float* Bp = Lmat + (size_t)k * DDIM * DDIM + (size_t)e * DDIM
                    + (lane >> 4) * 8;

    switch (nmt) {
        case 5: gmm_body<5>(Ap, Bp, mvec, rowmap, out, k, mh, e, cnt, lane); break;
        case 4: gmm_body<4>(Ap, Bp, mvec, rowmap, out, k, mh, e, cnt, lane); break;
        case 3: gmm_body<3>(Ap, Bp, mvec, rowmap, out, k, mh, e, cnt, lane); break;
        case 2: gmm_body<2>(Ap, Bp, mvec, rowmap, out, k, mh, e, cnt, lane); break;
        default: gmm_body<1>(Ap, Bp, mvec, rowmap, out, k, mh, e, cnt, lane); break;
    }
}

// ---------------- fallback (round-2 proven): fp32 LDS staging, tiny ws -----
__device__ __forceinline__ void async16(void* lds, const void* g) {
    __builtin_amdgcn_global_load_lds(
        (const __attribute__((address_space(1))) void*)g,
        (__attribute__((address_space(3))) void*)lds, 16, 0, 0);
}
__device__ __forceinline__ bf16x8 frag8(const char* base, int o0, int o1) {
    f32x4 x = *(const f32x4*)(base + o0);
    f32x4 y = *(const f32x4*)(base + o1);
    bf16x8 r;
#pragma unroll
    for (int i = 0; i < 4; ++i) { r[i] = bfs(x[i]); r[4 + i] = bfs(y[i]); }
    return r;
}
__global__ __launch_bounds__(256, 2)
void gmm_f32z(const float* __restrict__ z, const float* __restrict__ mvec,
              const float* __restrict__ Lmat, const int* __restrict__ rowmap,
              const int* __restrict__ counts, float* __restrict__ out) {
    __shared__ __attribute__((aligned(16))) char smem[2 * 28672];
    const int t = threadIdx.x, lane = t & 63, w = t >> 6;
    const int mh = w >> 1, nh = w & 1;
    const int k = blockIdx.y, n0 = blockIdx.x * 64;
    const float* Lk = Lmat + (size_t)k * DDIM * DDIM;
    const int rq = t >> 3;
    const int scol = ((t & 7) ^ (rq & 7)) * 4;
    int rm[5];
#pragma unroll
    for (int j = 0; j < 5; ++j)
        rm[j] = rowmap[k * MPAD + j * 32 + rq] & (BSAMP - 1);
    const unsigned ub = (unsigned)(t & ~63) * 16;
    auto stage = [&](int buf, int it) {
        char* lb = smem + buf * 28672;
        const int d0 = it * 32 + scol;
#pragma unroll
        for (int j = 0; j < 5; ++j)
            async16(lb + j * 4096 + ub, z + (size_t)rm[j] * DDIM + d0);
        async16(lb + 20480 + ub,        Lk + (size_t)(n0 + rq) * DDIM + d0);
        async16(lb + 20480 + 4096 + ub, Lk + (size_t)(n0 + 32 + rq) * DDIM + d0);
    };
    f32x4 acc[5][2];
#pragma unroll
    for (int mt = 0; mt < 5; ++mt)
#pragma unroll
        for (int nt = 0; nt < 2; ++nt) acc[mt][nt] = (f32x4){0.f, 0.f, 0.f, 0.f};
    stage(0, 0);
    __syncthreads();
    const int fr = lane & 15, g0 = (lane >> 4) * 2;
    for (int it = 0; it < DDIM / 32; ++it) {
        if (it + 1 < DDIM / 32) stage((it + 1) & 1, it + 1);
        const char* lb = smem + (it & 1) * 28672;
        const int rb0 = nh * 32 + fr, rb1 = rb0 + 16;
        bf16x8 b0 = frag8(lb + 20480, rb0 * 128 + ((g0 ^ rb0) & 7) * 16,
                          rb0 * 128 + (((g0 + 1) ^ rb0) & 7) * 16);
        bf16x8 b1 = frag8(lb + 20480, rb1 * 128 + ((g0 ^ rb1) & 7) * 16,
                          rb1 * 128 + (((g0 + 1) ^ rb1) & 7) * 16);
#pragma unroll
        for (int mt = 0; mt < 5; ++mt) {
            const int ra = mh * 80 + mt * 16 + fr;
            bf16x8 a = frag8(lb, ra * 128 + ((g0 ^ ra) & 7) * 16,
                             ra * 128 + (((g0 + 1) ^ ra) & 7) * 16);
            acc[mt][0] = __builtin_amdgcn_mfma_f32_16x16x32_bf16(a, b0, acc[mt][0], 0, 0, 0);
            acc[mt][1] = __builtin_amdgcn_mfma_f32_16x16x32_bf16(a, b1, acc[mt][1], 0, 0, 0);
        }
        __syncthreads();
    }
    const int cnt = counts[k], rquad = (lane >> 4) * 4;
#pragma unroll
    for (int nt = 0; nt < 2; ++nt) {
        const int e = n0 + nh * 32 + nt * 16 + fr;
        const float mu = mvec[k * DDIM + e];
#pragma unroll
        for (int mt = 0; mt < 5; ++mt) {
            const int sb = mh * 80 + mt * 16 + rquad;
#pragma unroll
            for (int r = 0; r < 4; ++r) {
                const int slot = sb + r;
                if (slot < cnt)
                    out[(size_t)rowmap[k * MPAD + slot] * DDIM + e] = acc[mt][nt][r] + mu;
            }
        }
    }
}

extern "C" void kernel_launch(void* const* d_in, const int* in_sizes, int n_in,
                              void* d_out, int out_size, void* d_ws, size_t ws_size,
                              hipStream_t stream) {
    const float* z    = (const float*)d_in[0];
    const float* mvec = (const float*)d_in[1];
    const float* Lmat = (const float*)d_in[2];
    const int* comp   = (const int*)d_in[3];
    float* out        = (float*)d_out;

    int* rowmap = (int*)d_ws;                     // 6400 B (+counts)
    int* counts = rowmap + KCOMP * MPAD;
    build_map<<<1, BSAMP, 0, stream>>>(comp, rowmap, counts);

    const size_t zf_off = 8192;
    const size_t zf_sz  = (size_t)KCOMP * 64 * 10 * 64 * 16;   // 6.4 MB

    if (ws_size >= zf_off + zf_sz) {
        short* zfrag = (short*)((char*)d_ws + zf_off);
        zprep<<<1600, 256, 0, stream>>>(z, rowmap, zfrag);
        gmm_direct<<<dim3(128, KCOMP), 128, 0, stream>>>(
            zfrag, mvec, Lmat, rowmap, counts, out);
    } else {
        gmm_f32z<<<dim3(32, KCOMP), 256, 0, stream>>>(
            z, mvec, Lmat, rowmap, counts, out);
    }
}

// Round 7
// 273.940 us; speedup vs baseline: 1.0725x; 1.0213x over previous
//
#include <hip/hip_runtime.h>
#include <hip/hip_bf16.h>

// out[b,e] = m[c,e] + sum_d z[b,d] * L[c,e,d],  c = components[b]
// fp32 in/out; bf16 MFMA. Round-7: single-wave blocks (64 thr), full-M tile
// (up to 160 rows) x 16 cols -> L streamed exactly once. Structurally-pinned
// register pipeline: ping-pong 4-slot B window (fills issued, then
// sched_barrier(0), then consume) + depth-1 A ping-pong. XCD-pinned k so
// zfrag (A frags) stays in the per-XCD 4MiB L2. B loads nontemporal.

#define DDIM  2048
#define BSAMP 1024
#define KCOMP 10
#define MPAD  160

typedef __attribute__((ext_vector_type(8))) short bf16x8;
typedef __attribute__((ext_vector_type(4))) float f32x4;

__device__ __forceinline__ short bfs(float x) {
    __hip_bfloat16 h = __float2bfloat16(x);
    return *reinterpret_cast<short*>(&h);
}

__global__ void build_map(const int* __restrict__ comp,
                          int* __restrict__ rowmap,
                          int* __restrict__ counts) {
    __shared__ int sc[KCOMP];
    const int t = threadIdx.x;
    if (t < KCOMP) sc[t] = 0;
    __syncthreads();
    const int c = comp[t];
    const int r = atomicAdd(&sc[c], 1);
    if (r < MPAD) rowmap[c * MPAD + r] = t;
    __syncthreads();
    if (t < KCOMP) counts[t] = sc[t];
}

// Pack z into A-fragment order: zfrag[((k*64+it)*10+ms)*64+lane] (16B items).
__global__ void zprep(const float* __restrict__ z,
                      const int* __restrict__ rowmap,
                      short* __restrict__ zfrag) {
    const int idx  = blockIdx.x * 256 + threadIdx.x;
    const int lane = idx & 63;
    const int rest = idx >> 6;
    const int ms   = rest % 10;
    const int kit  = rest / 10;
    const int it   = kit & 63;
    const int k    = kit >> 6;
    const int slot = ms * 16 + (lane & 15);
    const int r    = rowmap[k * MPAD + slot] & (BSAMP - 1);
    const int d    = it * 32 + (lane >> 4) * 8;
    const float* zp = z + (size_t)r * DDIM + d;
    f32x4 a = *(const f32x4*)zp;
    f32x4 b = *(const f32x4*)(zp + 4);
    bf16x8 o;
#pragma unroll
    for (int j = 0; j < 4; ++j) { o[j] = bfs(a[j]); o[4 + j] = bfs(b[j]); }
    *(bf16x8*)(zfrag + (size_t)idx * 8) = o;
}

template <int MT>
__device__ __forceinline__ void gmm_body(
        const short* __restrict__ Ap,   // A frag base (it=0), + lane*8
        const float* __restrict__ Bp,   // L row base for this lane
        const float* __restrict__ mvec,
        const int* __restrict__ rowmap,
        float* __restrict__ out,
        int k, int e, int cnt, int lane) {
    f32x4 acc[MT];
#pragma unroll
    for (int mt = 0; mt < MT; ++mt) acc[mt] = (f32x4){0.f, 0.f, 0.f, 0.f};

    f32x4 Ba[4][2], Bb[4][2];           // ping-pong B windows (4 iters each)
    bf16x8 A0[MT], A1[MT];              // A ping-pong (1 iter ahead)

#pragma unroll
    for (int j = 0; j < 4; ++j) {
        Ba[j][0] = __builtin_nontemporal_load((const f32x4*)(Bp + j * 32));
        Ba[j][1] = __builtin_nontemporal_load((const f32x4*)(Bp + j * 32 + 4));
    }
#pragma unroll
    for (int mt = 0; mt < MT; ++mt) A0[mt] = *(const bf16x8*)(Ap + mt * 512);

    // consume C[j] (iters it0..it0+3), fill N[j] (iters it0+4..it0+7)
    auto inner4 = [&](f32x4 (*C)[2], f32x4 (*N)[2], int it0) {
#pragma unroll
        for (int j = 0; j < 4; ++j) {
            int tf = it0 + 4 + j; tf = (tf > 63) ? 63 : tf;   // tail clamp
            const float* p = Bp + tf * 32;
            N[j][0] = __builtin_nontemporal_load((const f32x4*)(p));
            N[j][1] = __builtin_nontemporal_load((const f32x4*)(p + 4));
        }
        __builtin_amdgcn_sched_barrier(0);   // pin fills ABOVE consumption
#pragma unroll
        for (int j = 0; j < 4; ++j) {
            bf16x8* Ac = (j & 1) ? A1 : A0;
            bf16x8* An = (j & 1) ? A0 : A1;
            int ta = it0 + j + 1; ta = (ta > 63) ? 63 : ta;
            const short* ap = Ap + (size_t)ta * 5120;
#pragma unroll
            for (int mt = 0; mt < MT; ++mt)
                An[mt] = *(const bf16x8*)(ap + mt * 512);
            bf16x8 b;
#pragma unroll
            for (int i = 0; i < 4; ++i) {
                b[i]     = bfs(C[j][0][i]);
                b[4 + i] = bfs(C[j][1][i]);
            }
#pragma unroll
            for (int mt = 0; mt < MT; ++mt)
                acc[mt] = __builtin_amdgcn_mfma_f32_16x16x32_bf16(
                              Ac[mt], b, acc[mt], 0, 0, 0);
        }
    };

    for (int ot = 0; ot < 8; ++ot) {     // 8 x 8 = 64 iters
        inner4(Ba, Bb, ot * 8);
        inner4(Bb, Ba, ot * 8 + 4);
    }

    // epilogue: C/D col=lane&15, row=(lane>>4)*4+reg
    const float mu  = mvec[k * DDIM + e];
    const int rquad = (lane >> 4) * 4;
    const int rmB   = k * MPAD;
#pragma unroll
    for (int mt = 0; mt < MT; ++mt) {
#pragma unroll
        for (int r = 0; r < 4; ++r) {
            const int slot = mt * 16 + rquad + r;
            if (slot < cnt) {
                const int bidx = rowmap[rmB + slot];
                out[(size_t)bidx * DDIM + e] = acc[mt][r] + mu;
            }
        }
    }
}

// grid: 1280 1-D blocks of 64 (1 wave). Presumed XCD = blockIdx%8; all
// blocks of component k pinned to one XCD (k=8,9 split over 4 XCDs each)
// so the per-k zfrag slice (~655 KB) stays L2-resident. Wrong-mapping risk
// is perf-only.
__global__ __launch_bounds__(64, 1)
void gmm_direct(const short* __restrict__ zfrag,
                const float* __restrict__ mvec,
                const float* __restrict__ Lmat,
                const int* __restrict__ rowmap,
                const int* __restrict__ counts,
                float* __restrict__ out) {
    const int lane = threadIdx.x & 63;
    const int bid = blockIdx.x;
    const int x = bid & 7;               // presumed XCD
    const int o = bid >> 3;              // 0..159
    int k, n;
    if (o < 128) { k = x;               n = o; }
    else         { const int s = (o - 128) + x * 32;
                   k = 8 + (s >> 7);    n = s & 127; }

    const int cnt = counts[k];
    int mtc = (cnt + 15) >> 4;
    if (mtc > 10) mtc = 10;
    if (mtc < 1)  mtc = 1;

    const int e = n * 16 + (lane & 15);
    const short* Ap = zfrag + (size_t)(k * 64) * 10 * 512 + lane * 8;
    const float* Bp = Lmat + (size_t)k * DDIM * DDIM + (size_t)e * DDIM
                    + (lane >> 4) * 8;

    switch (mtc) {
        case 10: gmm_body<10>(Ap, Bp, mvec, rowmap, out, k, e, cnt, lane); break;
        case 9:  gmm_body<9 >(Ap, Bp, mvec, rowmap, out, k, e, cnt, lane); break;
        case 8:  gmm_body<8 >(Ap, Bp, mvec, rowmap, out, k, e, cnt, lane); break;
        case 7:  gmm_body<7 >(Ap, Bp, mvec, rowmap, out, k, e, cnt, lane); break;
        case 6:  gmm_body<6 >(Ap, Bp, mvec, rowmap, out, k, e, cnt, lane); break;
        case 5:  gmm_body<5 >(Ap, Bp, mvec, rowmap, out, k, e, cnt, lane); break;
        case 4:  gmm_body<4 >(Ap, Bp, mvec, rowmap, out, k, e, cnt, lane); break;
        case 3:  gmm_body<3 >(Ap, Bp, mvec, rowmap, out, k, e, cnt, lane); break;
        case 2:  gmm_body<2 >(Ap, Bp, mvec, rowmap, out, k, e, cnt, lane); break;
        default: gmm_body<1 >(Ap, Bp, mvec, rowmap, out, k, e, cnt, lane); break;
    }
}

// ---------------- fallback (round-2 proven): fp32 LDS staging, tiny ws -----
__device__ __forceinline__ void async16(void* lds, const void* g) {
    __builtin_amdgcn_global_load_lds(
        (const __attribute__((address_space(1))) void*)g,
        (__attribute__((address_space(3))) void*)lds, 16, 0, 0);
}
__device__ __forceinline__ bf16x8 frag8(const char* base, int o0, int o1) {
    f32x4 x = *(const f32x4*)(base + o0);
    f32x4 y = *(const f32x4*)(base + o1);
    bf16x8 r;
#pragma unroll
    for (int i = 0; i < 4; ++i) { r[i] = bfs(x[i]); r[4 + i] = bfs(y[i]); }
    return r;
}
__global__ __launch_bounds__(256, 2)
void gmm_f32z(const float* __restrict__ z, const float* __restrict__ mvec,
              const float* __restrict__ Lmat, const int* __restrict__ rowmap,
              const int* __restrict__ counts, float* __restrict__ out) {
    __shared__ __attribute__((aligned(16))) char smem[2 * 28672];
    const int t = threadIdx.x, lane = t & 63, w = t >> 6;
    const int mh = w >> 1, nh = w & 1;
    const int k = blockIdx.y, n0 = blockIdx.x * 64;
    const float* Lk = Lmat + (size_t)k * DDIM * DDIM;
    const int rq = t >> 3;
    const int scol = ((t & 7) ^ (rq & 7)) * 4;
    int rm[5];
#pragma unroll
    for (int j = 0; j < 5; ++j)
        rm[j] = rowmap[k * MPAD + j * 32 + rq] & (BSAMP - 1);
    const unsigned ub = (unsigned)(t & ~63) * 16;
    auto stage = [&](int buf, int it) {
        char* lb = smem + buf * 28672;
        const int d0 = it * 32 + scol;
#pragma unroll
        for (int j = 0; j < 5; ++j)
            async16(lb + j * 4096 + ub, z + (size_t)rm[j] * DDIM + d0);
        async16(lb + 20480 + ub,        Lk + (size_t)(n0 + rq) * DDIM + d0);
        async16(lb + 20480 + 4096 + ub, Lk + (size_t)(n0 + 32 + rq) * DDIM + d0);
    };
    f32x4 acc[5][2];
#pragma unroll
    for (int mt = 0; mt < 5; ++mt)
#pragma unroll
        for (int nt = 0; nt < 2; ++nt) acc[mt][nt] = (f32x4){0.f, 0.f, 0.f, 0.f};
    stage(0, 0);
    __syncthreads();
    const int fr = lane & 15, g0 = (lane >> 4) * 2;
    for (int it = 0; it < DDIM / 32; ++it) {
        if (it + 1 < DDIM / 32) stage((it + 1) & 1, it + 1);
        const char* lb = smem + (it & 1) * 28672;
        const int rb0 = nh * 32 + fr, rb1 = rb0 + 16;
        bf16x8 b0 = frag8(lb + 20480, rb0 * 128 + ((g0 ^ rb0) & 7) * 16,
                          rb0 * 128 + (((g0 + 1) ^ rb0) & 7) * 16);
        bf16x8 b1 = frag8(lb + 20480, rb1 * 128 + ((g0 ^ rb1) & 7) * 16,
                          rb1 * 128 + (((g0 + 1) ^ rb1) & 7) * 16);
#pragma unroll
        for (int mt = 0; mt < 5; ++mt) {
            const int ra = mh * 80 + mt * 16 + fr;
            bf16x8 a = frag8(lb, ra * 128 + ((g0 ^ ra) & 7) * 16,
                             ra * 128 + (((g0 + 1) ^ ra) & 7) * 16);
            acc[mt][0] = __builtin_amdgcn_mfma_f32_16x16x32_bf16(a, b0, acc[mt][0], 0, 0, 0);
            acc[mt][1] = __builtin_amdgcn_mfma_f32_16x16x32_bf16(a, b1, acc[mt][1], 0, 0, 0);
        }
        __syncthreads();
    }
    const int cnt = counts[k], rquad = (lane >> 4) * 4;
#pragma unroll
    for (int nt = 0; nt < 2; ++nt) {
        const int e = n0 + nh * 32 + nt * 16 + fr;
        const float mu = mvec[k * DDIM + e];
#pragma unroll
        for (int mt = 0; mt < 5; ++mt) {
            const int sb = mh * 80 + mt * 16 + rquad;
#pragma unroll
            for (int r = 0; r < 4; ++r) {
                const int slot = sb + r;
                if (slot < cnt)
                    out[(size_t)rowmap[k * MPAD + slot] * DDIM + e] = acc[mt][nt][r] + mu;
            }
        }
    }
}

extern "C" void kernel_launch(void* const* d_in, const int* in_sizes, int n_in,
                              void* d_out, int out_size, void* d_ws, size_t ws_size,
                              hipStream_t stream) {
    const float* z    = (const float*)d_in[0];
    const float* mvec = (const float*)d_in[1];
    const float* Lmat = (const float*)d_in[2];
    const int* comp   = (const int*)d_in[3];
    float* out        = (float*)d_out;

    int* rowmap = (int*)d_ws;                     // 6400 B (+counts)
    int* counts = rowmap + KCOMP * MPAD;
    build_map<<<1, BSAMP, 0, stream>>>(comp, rowmap, counts);

    const size_t zf_off = 8192;
    const size_t zf_sz  = (size_t)KCOMP * 64 * 10 * 64 * 16;   // 6.4 MB

    if (ws_size >= zf_off + zf_sz) {
        short* zfrag = (short*)((char*)d_ws + zf_off);
        zprep<<<1600, 256, 0, stream>>>(z, rowmap, zfrag);
        gmm_direct<<<1280, 64, 0, stream>>>(
            zfrag, mvec, Lmat, rowmap, counts, out);
    } else {
        gmm_f32z<<<dim3(32, KCOMP), 256, 0, stream>>>(
            z, mvec, Lmat, rowmap, counts, out);
    }
}